// Round 1
// baseline (153.814 us; speedup 1.0000x reference)
//
#include <hip/hip_runtime.h>

#define HH 512
#define WW 1024
#define HWSZ (HH*WW)
#define NCLS 19
#define KEEP 128
#define CTHR 0.1f

// ---------------- NMS (7x7, SAME, zero-equivalent padding) + candidate compaction ----------------
// tile 64x16 per 256-thread block; separable max in LDS
__global__ void nms_kernel(const float* __restrict__ hm_in, float* __restrict__ hm_out,
                           unsigned long long* __restrict__ keys, int* __restrict__ cnt, int cap)
{
    const int TX = 64, TY = 16;
    __shared__ float sin_[TY + 6][TX + 6];
    __shared__ float shm[TY + 6][TX];

    int bx = blockIdx.x % (WW / TX);
    int by = blockIdx.x / (WW / TX);
    int ox = bx * TX, oy = by * TY;

    // load halo tile, thresholded
    for (int i = threadIdx.x; i < (TY + 6) * (TX + 6); i += blockDim.x) {
        int ly = i / (TX + 6), lx = i % (TX + 6);
        int gy = oy + ly - 3, gx = ox + lx - 3;
        float v = 0.f;
        if (gy >= 0 && gy < HH && gx >= 0 && gx < WW) {
            float t = hm_in[gy * WW + gx];
            v = (t > CTHR) ? t : 0.f;
        }
        sin_[ly][lx] = v;
    }
    __syncthreads();

    // horizontal 7-max
    for (int i = threadIdx.x; i < (TY + 6) * TX; i += blockDim.x) {
        int ly = i / TX, lx = i % TX;
        float m = sin_[ly][lx];
#pragma unroll
        for (int d = 1; d < 7; d++) m = fmaxf(m, sin_[ly][lx + d]);
        shm[ly][lx] = m;
    }
    __syncthreads();

    // vertical 7-max + output + compact
    for (int i = threadIdx.x; i < TY * TX; i += blockDim.x) {
        int ly = i / TX, lx = i % TX;
        float m = shm[ly][lx];
#pragma unroll
        for (int d = 1; d < 7; d++) m = fmaxf(m, shm[ly + d][lx]);
        float c = sin_[ly + 3][lx + 3];
        float o = (m == c) ? c : 0.f;
        int gy = oy + ly, gx = ox + lx;
        hm_out[gy * WW + gx] = o;
        if (o > 0.f) {
            int pos = atomicAdd(cnt, 1);
            if (pos < cap) {
                unsigned int bits = __float_as_uint(o);
                unsigned int idx = (unsigned int)(gy * WW + gx);
                keys[pos] = ((unsigned long long)bits << 32) |
                            (unsigned long long)(0xFFFFFFFFu - idx);
            }
        }
    }
}

// ---------------- top-128 select: 2-pass radix narrow + bitonic sort (1 block) ----------------
__global__ void __launch_bounds__(1024) select_kernel(const unsigned long long* __restrict__ keys,
                                                      const int* __restrict__ cntp, int cap,
                                                      float4* __restrict__ centers)
{
    __shared__ unsigned int hist[2048];
    __shared__ unsigned int seg[64];
    __shared__ int s_bin, s_above, s_n;
    __shared__ unsigned long long buf[2048];

    int tid = threadIdx.x;
    int cnt = *cntp;
    if (cnt > cap) cnt = cap;
    int K = cnt < KEEP ? cnt : KEEP;

    // ---- pass 1: top 11 bits of key (= value bits >> 21)
    for (int i = tid; i < 2048; i += 1024) hist[i] = 0;
    __syncthreads();
    for (int c = tid; c < cnt; c += 1024)
        atomicAdd(&hist[(unsigned int)(keys[c] >> 53)], 1u);
    __syncthreads();
    if (tid < 64) { unsigned s = 0; for (int i = 0; i < 32; i++) s += hist[tid * 32 + i]; seg[tid] = s; }
    __syncthreads();
    if (tid == 0) {
        int acc = 0, B = 0;
        if (K > 0) {
            for (int sgi = 63; sgi >= 0; sgi--) {
                if (acc + (int)seg[sgi] >= K) {
                    for (int b = sgi * 32 + 31;; b--) {
                        if (acc + (int)hist[b] >= K) { B = b; break; }
                        acc += hist[b];
                    }
                    break;
                }
                acc += seg[sgi];
            }
        }
        s_bin = B; s_above = acc;
    }
    __syncthreads();
    int B1 = s_bin, above1 = s_above;
    int K2 = K - above1;

    // ---- pass 2: next 11 bits within bin B1
    for (int i = tid; i < 2048; i += 1024) hist[i] = 0;
    __syncthreads();
    for (int c = tid; c < cnt; c += 1024) {
        unsigned long long k64 = keys[c];
        if ((unsigned int)(k64 >> 53) == (unsigned int)B1)
            atomicAdd(&hist[(unsigned int)((k64 >> 42) & 2047u)], 1u);
    }
    __syncthreads();
    if (tid < 64) { unsigned s = 0; for (int i = 0; i < 32; i++) s += hist[tid * 32 + i]; seg[tid] = s; }
    __syncthreads();
    if (tid == 0) {
        int acc = 0, B = 0;
        if (K2 > 0) {
            for (int sgi = 63; sgi >= 0; sgi--) {
                if (acc + (int)seg[sgi] >= K2) {
                    for (int b = sgi * 32 + 31;; b--) {
                        if (acc + (int)hist[b] >= K2) { B = b; break; }
                        acc += hist[b];
                    }
                    break;
                }
                acc += seg[sgi];
            }
        }
        s_bin = B; s_n = 0;
    }
    __syncthreads();
    unsigned long long cutPrefix = (((unsigned long long)B1 << 11) | (unsigned long long)s_bin);

    // ---- collect everything at/above cutoff prefix
    for (int c = tid; c < cnt; c += 1024) {
        unsigned long long k64 = keys[c];
        if ((k64 >> 42) >= cutPrefix) {
            int pos = atomicAdd(&s_n, 1);
            if (pos < 2048) buf[pos] = k64;
        }
    }
    __syncthreads();
    int n = s_n; if (n > 2048) n = 2048;
    for (int i = tid; i < 2048; i += 1024) if (i >= n) buf[i] = 0ull;
    __syncthreads();

    // ---- bitonic sort descending (2048 virtual elems, 1024 threads)
    for (int kk = 2; kk <= 2048; kk <<= 1) {
        for (int j = kk >> 1; j > 0; j >>= 1) {
            for (int i = tid; i < 2048; i += 1024) {
                int ixj = i ^ j;
                if (ixj > i) {
                    bool desc = ((i & kk) == 0);
                    unsigned long long a = buf[i], b = buf[ixj];
                    if ((a < b) == desc) { buf[i] = b; buf[ixj] = a; }
                }
            }
            __syncthreads();
        }
    }

    if (tid < KEEP) {
        unsigned long long k64 = buf[tid];
        float sc, cy, cx, a;
        if (k64 == 0ull) {
            sc = 0.f; cy = 0.f; cx = 0.f; a = 0.f;   // padded/invalid center
        } else {
            sc = __uint_as_float((unsigned int)(k64 >> 32));
            unsigned int idx = 0xFFFFFFFFu - (unsigned int)(k64 & 0xFFFFFFFFu);
            cy = (float)(idx / WW);
            cx = (float)(idx % WW);
            a = cy * cy + cx * cx;                    // exact (< 2^24)
        }
        centers[tid] = make_float4(cy, cx, a, sc);
    }
}

// ---------------- fused semantic argmax + thing mask + nearest-center assignment ----------------
__global__ void assign_kernel(const float* __restrict__ logits, const float* __restrict__ offs,
                              const int* __restrict__ thing_ids, int n_thing,
                              const float4* __restrict__ centers, float* __restrict__ out)
{
    __shared__ float4 sc[KEEP];
    __shared__ int sids[32];
    int tid = threadIdx.x;
    if (tid < KEEP) sc[tid] = centers[tid];
    if (tid < n_thing) sids[tid] = thing_ids[tid];
    __syncthreads();

    int p = blockIdx.x * blockDim.x + tid;
    if (p >= HWSZ) return;

    // semantic argmax (first-wins on ties)
    const float* l = logits + (size_t)p * NCLS;
    float best = l[0];
    int cls = 0;
#pragma unroll
    for (int c = 1; c < NCLS; c++) {
        float v = l[c];
        if (v > best) { best = v; cls = c; }
    }
    bool thing = false;
    for (int j = 0; j < n_thing; j++) thing = thing || (cls == sids[j]);

    int h = p / WW, w = p % WW;
    float offy = offs[2 * p], offx = offs[2 * p + 1];
    float py = __fadd_rn((float)h, offy);
    float px = __fadd_rn((float)w, offx);
    float b = __fadd_rn(__fmul_rn(py, py), __fmul_rn(px, px));  // (cpp**2).sum(-1)

    float bestd = INFINITY;
    int bi = 0;
#pragma unroll 4
    for (int k = 0; k < KEEP; k++) {
        float4 c4 = sc[k];
        if (c4.w > 0.f) {  // valid center; invalid => d2 = inf (never taken)
            // replicate f32 gemm: m = fma(cx,px, rn(cy*py)); d2 = rn(rn(a-2m)+b)
            float m  = __fmaf_rn(c4.y, px, __fmul_rn(c4.x, py));
            float d2 = __fadd_rn(__fsub_rn(c4.z, __fadd_rn(m, m)), b);
            if (d2 < bestd) { bestd = d2; bi = k; }
        }
    }

    float inst = thing ? (float)(bi + 1) : 0.f;
    float smap = thing ? sc[bi].w : 0.f;
    out[p] = inst;                       // instance_seg
    out[2 * HWSZ + p] = smap;            // score_map
    out[3 * HWSZ + p] = (float)cls;      // semantic
}

extern "C" void kernel_launch(void* const* d_in, const int* in_sizes, int n_in,
                              void* d_out, int out_size, void* d_ws, size_t ws_size,
                              hipStream_t stream) {
    const float* logits = (const float*)d_in[0];
    const float* heat   = (const float*)d_in[1];
    const float* offs   = (const float*)d_in[2];
    const int*   tids   = (const int*)d_in[3];
    int n_thing = in_sizes[3];
    if (n_thing > 32) n_thing = 32;

    float* out = (float*)d_out;
    char* ws = (char*)d_ws;
    int* cnt = (int*)ws;                                   // [0,16)
    float4* centers = (float4*)(ws + 256);                 // 128 * 16B
    unsigned long long* keys = (unsigned long long*)(ws + 4096);
    long long cap64 = ((long long)ws_size - 4096) / 8;
    int cap = cap64 > 131072 ? 131072 : (int)cap64;
    if (cap < 0) cap = 0;

    hipMemsetAsync(cnt, 0, sizeof(int), stream);
    nms_kernel<<<dim3((WW / 64) * (HH / 16)), dim3(256), 0, stream>>>(heat, out + HWSZ, keys, cnt, cap);
    select_kernel<<<dim3(1), dim3(1024), 0, stream>>>(keys, cnt, cap, centers);
    assign_kernel<<<dim3(HWSZ / 256), dim3(256), 0, stream>>>(logits, offs, tids, n_thing, centers, out);
}

// Round 2
// 84.579 us; speedup vs baseline: 1.8186x; 1.8186x over previous
//
#include <hip/hip_runtime.h>

#define HH 512
#define WW 1024
#define HWSZ (HH*WW)
#define NCLS 19
#define KEEP 128
#define CTHR 0.1f

// ---------------- NMS (7x7, SAME) + block-aggregated candidate compaction ----------------
// tile 64x16 per 256-thread block; separable max in LDS; ONE global atomic per block
__global__ void nms_kernel(const float* __restrict__ hm_in, float* __restrict__ hm_out,
                           unsigned long long* __restrict__ keys, int* __restrict__ cnt, int cap)
{
    const int TX = 64, TY = 16;
    __shared__ float sin_[TY + 6][TX + 6];
    __shared__ float shm[TY + 6][TX];
    __shared__ unsigned long long lkeys[TX * TY];
    __shared__ int lcnt, lbase;

    if (threadIdx.x == 0) lcnt = 0;

    int bx = blockIdx.x % (WW / TX);
    int by = blockIdx.x / (WW / TX);
    int ox = bx * TX, oy = by * TY;

    // load halo tile, thresholded
    for (int i = threadIdx.x; i < (TY + 6) * (TX + 6); i += blockDim.x) {
        int ly = i / (TX + 6), lx = i % (TX + 6);
        int gy = oy + ly - 3, gx = ox + lx - 3;
        float v = 0.f;
        if (gy >= 0 && gy < HH && gx >= 0 && gx < WW) {
            float t = hm_in[gy * WW + gx];
            v = (t > CTHR) ? t : 0.f;
        }
        sin_[ly][lx] = v;
    }
    __syncthreads();

    // horizontal 7-max
    for (int i = threadIdx.x; i < (TY + 6) * TX; i += blockDim.x) {
        int ly = i / TX, lx = i % TX;
        float m = sin_[ly][lx];
#pragma unroll
        for (int d = 1; d < 7; d++) m = fmaxf(m, sin_[ly][lx + d]);
        shm[ly][lx] = m;
    }
    __syncthreads();

    // vertical 7-max + output + LDS compact
    for (int i = threadIdx.x; i < TY * TX; i += blockDim.x) {
        int ly = i / TX, lx = i % TX;
        float m = shm[ly][lx];
#pragma unroll
        for (int d = 1; d < 7; d++) m = fmaxf(m, shm[ly + d][lx]);
        float c = sin_[ly + 3][lx + 3];
        float o = (m == c) ? c : 0.f;
        int gy = oy + ly, gx = ox + lx;
        hm_out[gy * WW + gx] = o;
        if (o > 0.f) {
            int pos = atomicAdd(&lcnt, 1);
            unsigned int bits = __float_as_uint(o);
            unsigned int idx = (unsigned int)(gy * WW + gx);
            lkeys[pos] = ((unsigned long long)bits << 32) |
                         (unsigned long long)(0xFFFFFFFFu - idx);
        }
    }
    __syncthreads();
    if (threadIdx.x == 0) lbase = atomicAdd(cnt, lcnt);   // one global atomic per block
    __syncthreads();
    int n = lcnt, base = lbase;
    for (int i = threadIdx.x; i < n; i += blockDim.x) {
        int g = base + i;
        if (g < cap) keys[g] = lkeys[i];
    }
}

// ---------------- top-128 select: 2-pass radix narrow + dynamic-size bitonic sort ----------------
__global__ void __launch_bounds__(1024) select_kernel(const unsigned long long* __restrict__ keys,
                                                      const int* __restrict__ cntp, int cap,
                                                      float4* __restrict__ centers)
{
    __shared__ unsigned int hist[2048];
    __shared__ unsigned int seg[64];
    __shared__ int s_bin, s_above, s_n;
    __shared__ unsigned long long buf[2048];

    int tid = threadIdx.x;
    int cnt = *cntp;
    if (cnt > cap) cnt = cap;
    int K = cnt < KEEP ? cnt : KEEP;

    // ---- pass 1: top 11 bits of key (= value bits >> 21)
    for (int i = tid; i < 2048; i += 1024) hist[i] = 0;
    __syncthreads();
    for (int c = tid; c < cnt; c += 1024)
        atomicAdd(&hist[(unsigned int)(keys[c] >> 53)], 1u);
    __syncthreads();
    if (tid < 64) { unsigned s = 0; for (int i = 0; i < 32; i++) s += hist[tid * 32 + i]; seg[tid] = s; }
    __syncthreads();
    if (tid == 0) {
        int acc = 0, B = 0;
        if (K > 0) {
            for (int sgi = 63; sgi >= 0; sgi--) {
                if (acc + (int)seg[sgi] >= K) {
                    for (int b = sgi * 32 + 31;; b--) {
                        if (acc + (int)hist[b] >= K) { B = b; break; }
                        acc += hist[b];
                    }
                    break;
                }
                acc += seg[sgi];
            }
        }
        s_bin = B; s_above = acc;
    }
    __syncthreads();
    int B1 = s_bin, above1 = s_above;
    int K2 = K - above1;

    // ---- pass 2: next 11 bits within bin B1
    for (int i = tid; i < 2048; i += 1024) hist[i] = 0;
    __syncthreads();
    for (int c = tid; c < cnt; c += 1024) {
        unsigned long long k64 = keys[c];
        if ((unsigned int)(k64 >> 53) == (unsigned int)B1)
            atomicAdd(&hist[(unsigned int)((k64 >> 42) & 2047u)], 1u);
    }
    __syncthreads();
    if (tid < 64) { unsigned s = 0; for (int i = 0; i < 32; i++) s += hist[tid * 32 + i]; seg[tid] = s; }
    __syncthreads();
    if (tid == 0) {
        int acc = 0, B = 0;
        if (K2 > 0) {
            for (int sgi = 63; sgi >= 0; sgi--) {
                if (acc + (int)seg[sgi] >= K2) {
                    for (int b = sgi * 32 + 31;; b--) {
                        if (acc + (int)hist[b] >= K2) { B = b; break; }
                        acc += hist[b];
                    }
                    break;
                }
                acc += seg[sgi];
            }
        }
        s_bin = B; s_n = 0;
    }
    __syncthreads();
    unsigned long long cutPrefix = (((unsigned long long)B1 << 11) | (unsigned long long)s_bin);

    // ---- collect everything at/above cutoff prefix
    for (int c = tid; c < cnt; c += 1024) {
        unsigned long long k64 = keys[c];
        if ((k64 >> 42) >= cutPrefix) {
            int pos = atomicAdd(&s_n, 1);
            if (pos < 2048) buf[pos] = k64;
        }
    }
    __syncthreads();
    int n = s_n; if (n > 2048) n = 2048;
    int m = 256;                       // sort size: next pow2 >= n, min 256 (>= 2*KEEP)
    while (m < n) m <<= 1;
    for (int i = tid; i < m; i += 1024) if (i >= n) buf[i] = 0ull;
    __syncthreads();

    // ---- bitonic sort descending over m elements
    for (int kk = 2; kk <= m; kk <<= 1) {
        for (int j = kk >> 1; j > 0; j >>= 1) {
            for (int i = tid; i < m; i += 1024) {
                int ixj = i ^ j;
                if (ixj > i) {
                    bool desc = ((i & kk) == 0);
                    unsigned long long a = buf[i], b = buf[ixj];
                    if ((a < b) == desc) { buf[i] = b; buf[ixj] = a; }
                }
            }
            __syncthreads();
        }
    }

    if (tid < KEEP) {
        unsigned long long k64 = buf[tid];
        float sc, cy, cx, a;
        if (k64 == 0ull) {
            sc = 0.f; cy = 0.f; cx = 0.f; a = 0.f;   // padded/invalid center
        } else {
            sc = __uint_as_float((unsigned int)(k64 >> 32));
            unsigned int idx = 0xFFFFFFFFu - (unsigned int)(k64 & 0xFFFFFFFFu);
            cy = (float)(idx / WW);
            cx = (float)(idx % WW);
            a = cy * cy + cx * cx;                    // exact (< 2^24)
        }
        centers[tid] = make_float4(cy, cx, a, sc);
    }
}

// ---------------- fused semantic argmax + thing mask + nearest-center assignment ----------------
__global__ void __launch_bounds__(256) assign_kernel(
        const float* __restrict__ logits, const float* __restrict__ offs,
        const int* __restrict__ thing_ids, int n_thing,
        const float4* __restrict__ centers, float* __restrict__ out)
{
    __shared__ float4 sc[KEEP];
    __shared__ int sids[32];
    __shared__ float slog[256 * NCLS];     // 19456 B staged logits slab
    int tid = threadIdx.x;
    if (tid < KEEP) sc[tid] = centers[tid];
    if (tid < n_thing) sids[tid] = thing_ids[tid];

    int base = blockIdx.x * 256;
    // 256*19 floats = 1216 float4s, 16B-aligned (19456 % 16 == 0)
    const float4* l4 = (const float4*)(logits + (size_t)base * NCLS);
    float4* s4 = (float4*)slog;
    for (int i = tid; i < 256 * NCLS / 4; i += 256) s4[i] = l4[i];
    __syncthreads();

    int p = base + tid;

    // semantic argmax (first-wins on ties); stride-19 LDS reads, 19 coprime 32 -> conflict-free
    const float* l = slog + tid * NCLS;
    float best = l[0];
    int cls = 0;
#pragma unroll
    for (int c = 1; c < NCLS; c++) {
        float v = l[c];
        if (v > best) { best = v; cls = c; }
    }
    bool thing = false;
    for (int j = 0; j < n_thing; j++) thing = thing || (cls == sids[j]);

    int h = p / WW, w = p % WW;
    float2 off2 = ((const float2*)offs)[p];
    float py = __fadd_rn((float)h, off2.x);
    float px = __fadd_rn((float)w, off2.y);
    float b = __fadd_rn(__fmul_rn(py, py), __fmul_rn(px, px));  // (cpp**2).sum(-1)

    float bestd = INFINITY;
    int bi = 0;
#pragma unroll 4
    for (int k = 0; k < KEEP; k++) {
        float4 c4 = sc[k];
        if (c4.w > 0.f) {  // valid center; invalid => d2 = inf (never taken)
            // replicate f32 gemm: m = fma(cx,px, rn(cy*py)); d2 = rn(rn(a-2m)+b)
            float m  = __fmaf_rn(c4.y, px, __fmul_rn(c4.x, py));
            float d2 = __fadd_rn(__fsub_rn(c4.z, __fadd_rn(m, m)), b);
            if (d2 < bestd) { bestd = d2; bi = k; }
        }
    }

    float inst = thing ? (float)(bi + 1) : 0.f;
    float smap = thing ? sc[bi].w : 0.f;
    out[p] = inst;                       // instance_seg
    out[2 * HWSZ + p] = smap;            // score_map
    out[3 * HWSZ + p] = (float)cls;      // semantic
}

extern "C" void kernel_launch(void* const* d_in, const int* in_sizes, int n_in,
                              void* d_out, int out_size, void* d_ws, size_t ws_size,
                              hipStream_t stream) {
    const float* logits = (const float*)d_in[0];
    const float* heat   = (const float*)d_in[1];
    const float* offs   = (const float*)d_in[2];
    const int*   tids   = (const int*)d_in[3];
    int n_thing = in_sizes[3];
    if (n_thing > 32) n_thing = 32;

    float* out = (float*)d_out;
    char* ws = (char*)d_ws;
    int* cnt = (int*)ws;                                   // [0,16)
    float4* centers = (float4*)(ws + 256);                 // 128 * 16B
    unsigned long long* keys = (unsigned long long*)(ws + 4096);
    long long cap64 = ((long long)ws_size - 4096) / 8;
    int cap = cap64 > 131072 ? 131072 : (int)cap64;
    if (cap < 0) cap = 0;

    hipMemsetAsync(cnt, 0, sizeof(int), stream);
    nms_kernel<<<dim3((WW / 64) * (HH / 16)), dim3(256), 0, stream>>>(heat, out + HWSZ, keys, cnt, cap);
    select_kernel<<<dim3(1), dim3(1024), 0, stream>>>(keys, cnt, cap, centers);
    assign_kernel<<<dim3(HWSZ / 256), dim3(256), 0, stream>>>(logits, offs, tids, n_thing, centers, out);
}

// Round 3
// 61.178 us; speedup vs baseline: 2.5142x; 1.3825x over previous
//
#include <hip/hip_runtime.h>

#define HH 512
#define WW 1024
#define HWSZ (HH*WW)
#define NCLS 19
#define KEEP 128
#define CTHR 0.1f

// ---------------- NMS (7x7, SAME) + block-aggregated candidate compaction ----------------
__global__ void nms_kernel(const float* __restrict__ hm_in, float* __restrict__ hm_out,
                           unsigned long long* __restrict__ keys, int* __restrict__ cnt, int cap)
{
    const int TX = 64, TY = 16;
    __shared__ float sin_[TY + 6][TX + 6];
    __shared__ float shm[TY + 6][TX];
    __shared__ unsigned long long lkeys[TX * TY];
    __shared__ int lcnt, lbase;

    if (threadIdx.x == 0) lcnt = 0;

    int bx = blockIdx.x % (WW / TX);
    int by = blockIdx.x / (WW / TX);
    int ox = bx * TX, oy = by * TY;

    for (int i = threadIdx.x; i < (TY + 6) * (TX + 6); i += blockDim.x) {
        int ly = i / (TX + 6), lx = i % (TX + 6);
        int gy = oy + ly - 3, gx = ox + lx - 3;
        float v = 0.f;
        if (gy >= 0 && gy < HH && gx >= 0 && gx < WW) {
            float t = hm_in[gy * WW + gx];
            v = (t > CTHR) ? t : 0.f;
        }
        sin_[ly][lx] = v;
    }
    __syncthreads();

    for (int i = threadIdx.x; i < (TY + 6) * TX; i += blockDim.x) {
        int ly = i / TX, lx = i % TX;
        float m = sin_[ly][lx];
#pragma unroll
        for (int d = 1; d < 7; d++) m = fmaxf(m, sin_[ly][lx + d]);
        shm[ly][lx] = m;
    }
    __syncthreads();

    for (int i = threadIdx.x; i < TY * TX; i += blockDim.x) {
        int ly = i / TX, lx = i % TX;
        float m = shm[ly][lx];
#pragma unroll
        for (int d = 1; d < 7; d++) m = fmaxf(m, shm[ly + d][lx]);
        float c = sin_[ly + 3][lx + 3];
        float o = (m == c) ? c : 0.f;
        int gy = oy + ly, gx = ox + lx;
        hm_out[gy * WW + gx] = o;
        if (o > 0.f) {
            int pos = atomicAdd(&lcnt, 1);
            unsigned int bits = __float_as_uint(o);
            unsigned int idx = (unsigned int)(gy * WW + gx);
            lkeys[pos] = ((unsigned long long)bits << 32) |
                         (unsigned long long)(0xFFFFFFFFu - idx);
        }
    }
    __syncthreads();
    if (threadIdx.x == 0) lbase = atomicAdd(cnt, lcnt);   // one global atomic per block
    __syncthreads();
    int n = lcnt, base = lbase;
    for (int i = threadIdx.x; i < n; i += blockDim.x) {
        int g = base + i;
        if (g < cap) keys[g] = lkeys[i];
    }
}

// ---------------- top-128 select: 2-pass radix narrow + dynamic-size bitonic sort ----------------
__global__ void __launch_bounds__(1024) select_kernel(const unsigned long long* __restrict__ keys,
                                                      const int* __restrict__ cntp, int cap,
                                                      float4* __restrict__ centers)
{
    __shared__ unsigned int hist[2048];
    __shared__ unsigned int seg[64];
    __shared__ int s_bin, s_above, s_n;
    __shared__ unsigned long long buf[2048];

    int tid = threadIdx.x;
    int cnt = *cntp;
    if (cnt > cap) cnt = cap;
    int K = cnt < KEEP ? cnt : KEEP;

    for (int i = tid; i < 2048; i += 1024) hist[i] = 0;
    __syncthreads();
    for (int c = tid; c < cnt; c += 1024)
        atomicAdd(&hist[(unsigned int)(keys[c] >> 53)], 1u);
    __syncthreads();
    if (tid < 64) { unsigned s = 0; for (int i = 0; i < 32; i++) s += hist[tid * 32 + i]; seg[tid] = s; }
    __syncthreads();
    if (tid == 0) {
        int acc = 0, B = 0;
        if (K > 0) {
            for (int sgi = 63; sgi >= 0; sgi--) {
                if (acc + (int)seg[sgi] >= K) {
                    for (int b = sgi * 32 + 31;; b--) {
                        if (acc + (int)hist[b] >= K) { B = b; break; }
                        acc += hist[b];
                    }
                    break;
                }
                acc += seg[sgi];
            }
        }
        s_bin = B; s_above = acc;
    }
    __syncthreads();
    int B1 = s_bin, above1 = s_above;
    int K2 = K - above1;

    for (int i = tid; i < 2048; i += 1024) hist[i] = 0;
    __syncthreads();
    for (int c = tid; c < cnt; c += 1024) {
        unsigned long long k64 = keys[c];
        if ((unsigned int)(k64 >> 53) == (unsigned int)B1)
            atomicAdd(&hist[(unsigned int)((k64 >> 42) & 2047u)], 1u);
    }
    __syncthreads();
    if (tid < 64) { unsigned s = 0; for (int i = 0; i < 32; i++) s += hist[tid * 32 + i]; seg[tid] = s; }
    __syncthreads();
    if (tid == 0) {
        int acc = 0, B = 0;
        if (K2 > 0) {
            for (int sgi = 63; sgi >= 0; sgi--) {
                if (acc + (int)seg[sgi] >= K2) {
                    for (int b = sgi * 32 + 31;; b--) {
                        if (acc + (int)hist[b] >= K2) { B = b; break; }
                        acc += hist[b];
                    }
                    break;
                }
                acc += seg[sgi];
            }
        }
        s_bin = B; s_n = 0;
    }
    __syncthreads();
    unsigned long long cutPrefix = (((unsigned long long)B1 << 11) | (unsigned long long)s_bin);

    for (int c = tid; c < cnt; c += 1024) {
        unsigned long long k64 = keys[c];
        if ((k64 >> 42) >= cutPrefix) {
            int pos = atomicAdd(&s_n, 1);
            if (pos < 2048) buf[pos] = k64;
        }
    }
    __syncthreads();
    int n = s_n; if (n > 2048) n = 2048;
    int m = 256;                       // next pow2 >= n, min 256 (>= 2*KEEP)
    while (m < n) m <<= 1;
    for (int i = tid; i < m; i += 1024) if (i >= n) buf[i] = 0ull;
    __syncthreads();

    for (int kk = 2; kk <= m; kk <<= 1) {
        for (int j = kk >> 1; j > 0; j >>= 1) {
            for (int i = tid; i < m; i += 1024) {
                int ixj = i ^ j;
                if (ixj > i) {
                    bool desc = ((i & kk) == 0);
                    unsigned long long a = buf[i], b = buf[ixj];
                    if ((a < b) == desc) { buf[i] = b; buf[ixj] = a; }
                }
            }
            __syncthreads();
        }
    }

    if (tid < KEEP) {
        unsigned long long k64 = buf[tid];
        float sc, cy, cx, a;
        if (k64 == 0ull) {
            sc = 0.f; cy = 0.f; cx = 0.f; a = 0.f;
        } else {
            sc = __uint_as_float((unsigned int)(k64 >> 32));
            unsigned int idx = 0xFFFFFFFFu - (unsigned int)(k64 & 0xFFFFFFFFu);
            cy = (float)(idx / WW);
            cx = (float)(idx % WW);
            a = cy * cy + cx * cx;                    // exact (< 2^24)
        }
        centers[tid] = make_float4(cy, cx, a, sc);
    }
}

// ---------------- fused argmax + thing mask + PRUNED nearest-center assignment ----------------
// 16x16 pixel tiles; conservative box-bound pruning of the 128-center list.
__global__ void __launch_bounds__(256) assign_kernel(
        const float* __restrict__ logits, const float* __restrict__ offs,
        const int* __restrict__ thing_ids, int n_thing,
        const float4* __restrict__ centers, float* __restrict__ out)
{
    __shared__ float4 sc[KEEP];
    __shared__ float4 skept[KEEP];
    __shared__ int   skidx[KEEP];
    __shared__ float slog[256 * NCLS];
    __shared__ float sred[16];
    __shared__ float ured[4];
    __shared__ int   wcnt[4];
    __shared__ int   s_nkept;
    __shared__ int   sids[32];

    int tid = threadIdx.x;
    if (tid < KEEP) sc[tid] = centers[tid];
    if (tid < n_thing) sids[tid] = thing_ids[tid];

    int bx = blockIdx.x & 63;          // WW/16 tiles across
    int by = blockIdx.x >> 6;
    int lr = tid >> 4, lc = tid & 15;
    int gy = by * 16 + lr, gx = bx * 16 + lc;
    int p  = gy * WW + gx;

    // stage logits tile: 16 rows x (16 px * 19) floats, coalesced dword runs of 1216B
    {
        const float* src = logits + ((size_t)(by * 16) * WW + bx * 16) * NCLS;
        for (int i = tid; i < 16 * 304; i += 256) {
            int r = i / 304, c = i % 304;
            slog[i] = src[(size_t)r * WW * NCLS + c];
        }
    }

    float2 off2 = ((const float2*)offs)[p];
    float py = __fadd_rn((float)gy, off2.x);
    float px = __fadd_rn((float)gx, off2.y);

    // block-wide bounding box of (py,px)
    float ymn = py, ymx = py, xmn = px, xmx = px;
    for (int d = 32; d; d >>= 1) {
        ymn = fminf(ymn, __shfl_xor(ymn, d));
        ymx = fmaxf(ymx, __shfl_xor(ymx, d));
        xmn = fminf(xmn, __shfl_xor(xmn, d));
        xmx = fmaxf(xmx, __shfl_xor(xmx, d));
    }
    if ((tid & 63) == 0) {
        int w = tid >> 6;
        sred[w * 4 + 0] = ymn; sred[w * 4 + 1] = ymx;
        sred[w * 4 + 2] = xmn; sred[w * 4 + 3] = xmx;
    }
    __syncthreads();   // slog, sred, sc, sids all ready

    ymn = fminf(fminf(sred[0], sred[4]), fminf(sred[8],  sred[12]));
    ymx = fmaxf(fmaxf(sred[1], sred[5]), fmaxf(sred[9],  sred[13]));
    xmn = fminf(fminf(sred[2], sred[6]), fminf(sred[10], sred[14]));
    xmx = fmaxf(fmaxf(sred[3], sred[7]), fmaxf(sred[11], sred[15]));

    // per-center bounds (threads 0..127)
    float L = INFINITY, U = INFINITY;
    bool valid = false;
    if (tid < KEEP) {
        float4 c4 = sc[tid];
        valid = (c4.w > 0.f);
        if (valid) {
            float dyl = fmaxf(fmaxf(ymn - c4.x, c4.x - ymx), 0.f);
            float dxl = fmaxf(fmaxf(xmn - c4.y, c4.y - xmx), 0.f);
            L = dyl * dyl + dxl * dxl;
            float dyu = fmaxf(fabsf(c4.x - ymn), fabsf(c4.x - ymx));
            float dxu = fmaxf(fabsf(c4.y - xmn), fabsf(c4.y - xmx));
            U = dyu * dyu + dxu * dxu;
        }
    }
    // min over valid centers of U
    float u = U;
    for (int d = 32; d; d >>= 1) u = fminf(u, __shfl_xor(u, d));
    if ((tid & 63) == 0) ured[tid >> 6] = u;
    __syncthreads();
    float Umin = fminf(fminf(ured[0], ured[1]), fminf(ured[2], ured[3]));

    // keep flags + order-preserving compaction (margin 8 >> max rounding slop ~2)
    bool keep = valid && (L <= Umin + 8.0f);
    unsigned long long mask = __ballot(keep);
    int lane = tid & 63;
    int prefix = __popcll(mask & ((1ull << lane) - 1ull));
    if (lane == 0) wcnt[tid >> 6] = __popcll(mask);
    __syncthreads();
    int base = (tid >> 6) == 1 ? wcnt[0] : 0;
    if (keep) { skept[base + prefix] = sc[tid]; skidx[base + prefix] = tid; }
    if (tid == 0) s_nkept = wcnt[0] + wcnt[1];
    __syncthreads();

    // semantic argmax (first-wins); stride-19 LDS, conflict-free
    const float* l = slog + tid * NCLS;
    float best = l[0];
    int cls = 0;
#pragma unroll
    for (int c = 1; c < NCLS; c++) {
        float v = l[c];
        if (v > best) { best = v; cls = c; }
    }
    bool thing = false;
    for (int j = 0; j < n_thing; j++) thing = thing || (cls == sids[j]);

    float b = __fadd_rn(__fmul_rn(py, py), __fmul_rn(px, px));

    float bestd = INFINITY;
    int bi = -1;
    int nk = s_nkept;
    for (int k = 0; k < nk; k++) {
        float4 c4 = skept[k];
        // replicate f32 gemm: m = fma(cx,px, rn(cy*py)); d2 = rn(rn(a-2m)+b)
        float m  = __fmaf_rn(c4.y, px, __fmul_rn(c4.x, py));
        float d2 = __fadd_rn(__fsub_rn(c4.z, __fadd_rn(m, m)), b);
        if (d2 < bestd) { bestd = d2; bi = k; }
    }

    float inst, smap;
    if (bi < 0) { inst = thing ? 1.f : 0.f; smap = 0.f; }   // no valid centers: argmin=0
    else {
        inst = thing ? (float)(skidx[bi] + 1) : 0.f;
        smap = thing ? skept[bi].w : 0.f;
    }
    out[p] = inst;
    out[2 * HWSZ + p] = smap;
    out[3 * HWSZ + p] = (float)cls;
}

extern "C" void kernel_launch(void* const* d_in, const int* in_sizes, int n_in,
                              void* d_out, int out_size, void* d_ws, size_t ws_size,
                              hipStream_t stream) {
    const float* logits = (const float*)d_in[0];
    const float* heat   = (const float*)d_in[1];
    const float* offs   = (const float*)d_in[2];
    const int*   tids   = (const int*)d_in[3];
    int n_thing = in_sizes[3];
    if (n_thing > 32) n_thing = 32;

    float* out = (float*)d_out;
    char* ws = (char*)d_ws;
    int* cnt = (int*)ws;
    float4* centers = (float4*)(ws + 256);
    unsigned long long* keys = (unsigned long long*)(ws + 4096);
    long long cap64 = ((long long)ws_size - 4096) / 8;
    int cap = cap64 > 131072 ? 131072 : (int)cap64;
    if (cap < 0) cap = 0;

    hipMemsetAsync(cnt, 0, sizeof(int), stream);
    nms_kernel<<<dim3((WW / 64) * (HH / 16)), dim3(256), 0, stream>>>(heat, out + HWSZ, keys, cnt, cap);
    select_kernel<<<dim3(1), dim3(1024), 0, stream>>>(keys, cnt, cap, centers);
    assign_kernel<<<dim3((WW / 16) * (HH / 16)), dim3(256), 0, stream>>>(logits, offs, tids, n_thing, centers, out);
}